// Round 1
// baseline (568.122 us; speedup 1.0000x reference)
//
#include <hip/hip_runtime.h>
#include <hip/hip_bf16.h>

namespace {
constexpr int CB   = 256;   // channels
constexpr int HWp  = 4096;  // 64*64 pixels per plane
constexpr int NB   = 16;    // batch
constexpr int PADK = 15;

typedef __bf16 bf16x8 __attribute__((ext_vector_type(8)));
typedef float  f32x4  __attribute__((ext_vector_type(4)));

typedef __attribute__((address_space(1))) void gvoid;  // global
typedef __attribute__((address_space(3))) void svoid;  // LDS
}

// ---------------------------------------------------------------------------
// Kernel 1: depthwise 31x31 conv (fp32) + per-channel sum/sumsq partials.
// One block per (b,c) plane. LDS halo tile 94 rows x 100-stride floats.
// Each thread: one output row strip of 16 (h = tid>>2, w0 = (tid&3)*16).
// ---------------------------------------------------------------------------
__global__ __launch_bounds__(256, 3) void dwconv_kernel(
    const float* __restrict__ x, const float* __restrict__ dw,
    float* __restrict__ y, float* __restrict__ gsum, float* __restrict__ gsumsq)
{
    __shared__ float xs[94 * 100];   // row stride 100 floats (400 B -> 2-way banks only)
    __shared__ float wsp[31 * 32];   // 31x31 weights padded to stride 32

    const int bc  = blockIdx.x;
    const int c   = bc & (CB - 1);
    const int tid = threadIdx.x;
    const float* __restrict__ xp = x + (size_t)bc * HWp;

    // Fill halo tile (zero-padded). Cols 0..95 filled; reads touch <=95.
    for (int idx = tid; idx < 94 * 96; idx += 256) {
        const int r  = idx / 96;
        const int cc = idx - r * 96;
        const int gr = r - PADK, gc = cc - PADK;
        float v = 0.f;
        if ((unsigned)gr < 64u && (unsigned)gc < 64u) v = xp[gr * 64 + gc];
        xs[r * 100 + cc] = v;
    }
    // Weights for this channel into LDS (padded rows for float4 loads).
    const float* __restrict__ wp = dw + (size_t)c * 961;
    for (int idx = tid; idx < 31 * 32; idx += 256) {
        const int i = idx >> 5, j = idx & 31;
        wsp[idx] = (j < 31) ? wp[i * 31 + j] : 0.f;
    }
    __syncthreads();

    const int h  = tid >> 2;
    const int w0 = (tid & 3) << 4;

    float acc[16];
#pragma unroll
    for (int t = 0; t < 16; ++t) acc[t] = 0.f;

#pragma unroll 1
    for (int i = 0; i < 31; ++i) {
        float xr[48];
        const float4* __restrict__ xsrc =
            reinterpret_cast<const float4*>(&xs[(h + i) * 100 + w0]);
#pragma unroll
        for (int q = 0; q < 12; ++q) reinterpret_cast<float4*>(xr)[q] = xsrc[q];

        float wv[32];
        const float4* __restrict__ wsrc =
            reinterpret_cast<const float4*>(&wsp[i * 32]);
#pragma unroll
        for (int q = 0; q < 8; ++q) reinterpret_cast<float4*>(wv)[q] = wsrc[q];

#pragma unroll
        for (int j = 0; j < 31; ++j)
#pragma unroll
            for (int t = 0; t < 16; ++t)
                acc[t] = fmaf(wv[j], xr[t + j], acc[t]);
    }

    // Store y (fp32, into d_out buffer) — 4x float4, coalesced.
    float* __restrict__ yp = y + (size_t)bc * HWp + h * 64 + w0;
#pragma unroll
    for (int q = 0; q < 4; ++q)
        reinterpret_cast<float4*>(yp)[q] = *reinterpret_cast<float4*>(&acc[4 * q]);

    // Per-channel stats: thread partial -> wave shuffle reduce -> one atomic/wave.
    float s = 0.f, s2 = 0.f;
#pragma unroll
    for (int t = 0; t < 16; ++t) { s += acc[t]; s2 = fmaf(acc[t], acc[t], s2); }
#pragma unroll
    for (int off = 32; off > 0; off >>= 1) {
        s  += __shfl_down(s,  off, 64);
        s2 += __shfl_down(s2, off, 64);
    }
    if ((tid & 63) == 0) {
        atomicAdd(&gsum[c],   s);
        atomicAdd(&gsumsq[c], s2);
    }
}

// ---------------------------------------------------------------------------
// Kernel 2: finalize stats -> per-channel scale/shift; convert pw to bf16.
// ---------------------------------------------------------------------------
__global__ __launch_bounds__(256) void stats_kernel(
    const float* __restrict__ gsum, const float* __restrict__ gsumsq,
    const float* __restrict__ gamma, const float* __restrict__ beta,
    const float* __restrict__ pw,
    float* __restrict__ scale, float* __restrict__ shift,
    __hip_bfloat16* __restrict__ pwb)
{
    const int tid = threadIdx.x;
    const float inv = 1.f / 65536.f;
    const float mean = gsum[tid] * inv;
    const float var  = gsumsq[tid] * inv - mean * mean;
    const float sc   = gamma[tid] * rsqrtf(var + 1e-5f);
    scale[tid] = sc;
    shift[tid] = beta[tid] - mean * sc;

    for (int idx = tid; idx < CB * CB; idx += 256)
        pwb[idx] = __float2bfloat16(pw[idx]);
}

// ---------------------------------------------------------------------------
// Kernel 3: normalize + ReLU + bf16 + transpose:  y[b][c][p] -> rt[b][p][c]
// 32x32 tiles through LDS.
// ---------------------------------------------------------------------------
__global__ __launch_bounds__(256) void normtrans_kernel(
    const float* __restrict__ y, const float* __restrict__ scale,
    const float* __restrict__ shift, __hip_bfloat16* __restrict__ rt)
{
    __shared__ __hip_bfloat16 tile[32][33];
    const int b   = blockIdx.z;
    const int c0  = blockIdx.y * 32;
    const int p0  = blockIdx.x * 32;
    const int tid = threadIdx.x;

    {   // coalesced read along p
        const int cl  = tid >> 3;
        const int pl4 = (tid & 7) * 4;
        const float4 v = *reinterpret_cast<const float4*>(
            y + (size_t)(b * CB + c0 + cl) * HWp + p0 + pl4);
        const float sc = scale[c0 + cl], sh = shift[c0 + cl];
        tile[cl][pl4 + 0] = __float2bfloat16(fmaxf(fmaf(v.x, sc, sh), 0.f));
        tile[cl][pl4 + 1] = __float2bfloat16(fmaxf(fmaf(v.y, sc, sh), 0.f));
        tile[cl][pl4 + 2] = __float2bfloat16(fmaxf(fmaf(v.z, sc, sh), 0.f));
        tile[cl][pl4 + 3] = __float2bfloat16(fmaxf(fmaf(v.w, sc, sh), 0.f));
    }
    __syncthreads();
    {   // coalesced write along c
        const int pl  = tid >> 3;
        const int cl4 = (tid & 7) * 4;
        union { __hip_bfloat16 h[4]; uint2 u; } pk;
#pragma unroll
        for (int k2 = 0; k2 < 4; ++k2) pk.h[k2] = tile[cl4 + k2][pl];
        *reinterpret_cast<uint2*>(
            rt + ((size_t)b * HWp + p0 + pl) * CB + c0 + cl4) = pk.u;
    }
}

// ---------------------------------------------------------------------------
// Kernel 4: pointwise conv as bf16 MFMA GEMM.
// out[b][o][p] = sum_c pw[o][c] * rt[b][p][c].   M=256(o), N=4096/batch(p), K=256(c)
// Block: 256 thr = 4 waves (2x2), tile 128x128, BK=32, global_load_lds staging.
// ---------------------------------------------------------------------------
__global__ __launch_bounds__(256, 2) void gemm_kernel(
    const __hip_bfloat16* __restrict__ pwb, const __hip_bfloat16* __restrict__ rt,
    float* __restrict__ out)
{
    __shared__ __hip_bfloat16 ldsA[128 * 32];  // [o-row][c] 64B rows
    __shared__ __hip_bfloat16 ldsB[128 * 32];  // [p-row][c] 64B rows

    const int tid  = threadIdx.x;
    const int lane = tid & 63;
    const int wid  = tid >> 6;
    const int b    = blockIdx.z;
    const int m0   = blockIdx.y * 128;
    const int p0   = blockIdx.x * 128;
    const int wm   = wid >> 1, wn = wid & 1;

    f32x4 acc[4][4];
#pragma unroll
    for (int mi = 0; mi < 4; ++mi)
#pragma unroll
        for (int ni = 0; ni < 4; ++ni) acc[mi][ni] = {0.f, 0.f, 0.f, 0.f};

    const int srow = lane >> 2;        // row within a 16-row staging issue
    const int scol = (lane & 3) * 8;   // bf16 col offset (8 elems = 16B)
    const int fr   = lane & 15;
    const int fk   = (lane >> 4) * 8;

    const size_t rtbase = (size_t)b * HWp;

    for (int ks = 0; ks < 8; ++ks) {
        const int k0 = ks * 32;
#pragma unroll
        for (int q = 0; q < 2; ++q) {
            const int issue = wid * 2 + q;       // 0..7, 16 rows each
            const int row   = issue * 16 + srow;
            const __hip_bfloat16* gA = pwb + (size_t)(m0 + row) * CB + k0 + scol;
            const __hip_bfloat16* gB = rt + (rtbase + p0 + row) * CB + k0 + scol;
            __builtin_amdgcn_global_load_lds((gvoid*)gA, (svoid*)(ldsA + issue * 512), 16, 0, 0);
            __builtin_amdgcn_global_load_lds((gvoid*)gB, (svoid*)(ldsB + issue * 512), 16, 0, 0);
        }
        __syncthreads();

        bf16x8 af[4], bfr[4];
#pragma unroll
        for (int mi = 0; mi < 4; ++mi)
            af[mi] = *reinterpret_cast<const bf16x8*>(
                ldsA + (wm * 64 + mi * 16 + fr) * 32 + fk);
#pragma unroll
        for (int ni = 0; ni < 4; ++ni)
            bfr[ni] = *reinterpret_cast<const bf16x8*>(
                ldsB + (wn * 64 + ni * 16 + fr) * 32 + fk);

#pragma unroll
        for (int mi = 0; mi < 4; ++mi)
#pragma unroll
            for (int ni = 0; ni < 4; ++ni)
                acc[mi][ni] = __builtin_amdgcn_mfma_f32_16x16x32_bf16(
                    af[mi], bfr[ni], acc[mi][ni], 0, 0, 0);
        __syncthreads();
    }

    // Epilogue: D col = lane&15 (p), row = (lane>>4)*4 + v (o). [m89-verified]
    const int frow = (lane >> 4) * 4;
#pragma unroll
    for (int mi = 0; mi < 4; ++mi)
#pragma unroll
        for (int ni = 0; ni < 4; ++ni)
#pragma unroll
            for (int v = 0; v < 4; ++v) {
                const int o = m0 + wm * 64 + mi * 16 + frow + v;
                const int p = p0 + wn * 64 + ni * 16 + fr;
                out[((size_t)(b * CB + o)) * HWp + p] = acc[mi][ni][v];
            }
}

// ---------------------------------------------------------------------------
extern "C" void kernel_launch(void* const* d_in, const int* in_sizes, int n_in,
                              void* d_out, int out_size, void* d_ws, size_t ws_size,
                              hipStream_t stream) {
    (void)in_sizes; (void)n_in; (void)out_size; (void)ws_size;
    const float* x     = (const float*)d_in[0];
    const float* dw    = (const float*)d_in[1];
    const float* gamma = (const float*)d_in[2];
    const float* beta  = (const float*)d_in[3];
    const float* pw    = (const float*)d_in[4];
    float* out = (float*)d_out;

    // Workspace layout: rt (32 MB) | gsum | gsumsq | scale | shift | pwb (128 KB)
    char* ws = (char*)d_ws;
    __hip_bfloat16* rt = (__hip_bfloat16*)ws;
    float* gsum   = (float*)(ws + (size_t)33554432);
    float* gsumsq = gsum + 256;
    float* scale  = gsum + 512;
    float* shift  = gsum + 768;
    __hip_bfloat16* pwb = (__hip_bfloat16*)(ws + (size_t)33554432 + 4096);

    hipMemsetAsync(gsum, 0, 2048, stream);

    // y (fp32) lives in d_out; GEMM overwrites it at the end.
    dwconv_kernel<<<dim3(NB * CB), 256, 0, stream>>>(x, dw, out, gsum, gsumsq);
    stats_kernel<<<dim3(1), 256, 0, stream>>>(gsum, gsumsq, gamma, beta, pw,
                                              scale, shift, pwb);
    normtrans_kernel<<<dim3(128, 8, NB), 256, 0, stream>>>(out, scale, shift, rt);
    gemm_kernel<<<dim3(32, 2, NB), 256, 0, stream>>>(pwb, rt, out);
}

// Round 2
// 400.920 us; speedup vs baseline: 1.4170x; 1.4170x over previous
//
#include <hip/hip_runtime.h>
#include <hip/hip_bf16.h>

namespace {
constexpr int CB   = 256;   // channels
constexpr int HWp  = 4096;  // 64*64 pixels per plane
constexpr int NB   = 16;    // batch
constexpr int PADK = 15;

typedef __bf16    bf16x8 __attribute__((ext_vector_type(8)));
typedef float     f32x4  __attribute__((ext_vector_type(4)));
typedef _Float16  f16x2  __attribute__((ext_vector_type(2)));

typedef __attribute__((address_space(1))) void gvoid;  // global
typedef __attribute__((address_space(3))) void svoid;  // LDS

__device__ __forceinline__ float dot2(unsigned int a, unsigned int b, float c) {
#if __has_builtin(__builtin_amdgcn_fdot2)
    return __builtin_amdgcn_fdot2(__builtin_bit_cast(f16x2, a),
                                  __builtin_bit_cast(f16x2, b), c, false);
#else
    f16x2 av = __builtin_bit_cast(f16x2, a), bv = __builtin_bit_cast(f16x2, b);
    return fmaf((float)av[0], (float)bv[0], fmaf((float)av[1], (float)bv[1], c));
#endif
}

__device__ __forceinline__ unsigned int pack2(float lo, float hi) {
#if __has_builtin(__builtin_amdgcn_cvt_pkrtz)
    return __builtin_bit_cast(unsigned int, __builtin_amdgcn_cvt_pkrtz(lo, hi));
#else
    f16x2 v; v[0] = (_Float16)lo; v[1] = (_Float16)hi;
    return __builtin_bit_cast(unsigned int, v);
#endif
}
}

// ---------------------------------------------------------------------------
// Kernel 1: depthwise 31x31 conv via v_dot2_f32_f16 + per-channel sum/sumsq.
// One block per (b,c) plane. Halo tile as f16 PAIRS in LDS: 94 rows x 48 pairs
// (stride 52 u32 = 208 B, 16B-aligned rows). Two weight packings per kernel
// row: wA=(w0,w1)..(w30,0) for even out-cols, wB=(0,w0),(w1,w2)..(w29,w30)
// for odd out-cols -> every output reads only ALIGNED x pairs.
// Thread: 16 outputs (h = tid>>2, w0 = (tid&3)*16). 256 dot2 / row-tap.
// ---------------------------------------------------------------------------
__global__ __launch_bounds__(256, 6) void dwconv_kernel(
    const float* __restrict__ x, const float* __restrict__ dw,
    float* __restrict__ y, float* __restrict__ gsum, float* __restrict__ gsumsq)
{
    __shared__ unsigned int xs2[94 * 52];   // 19552 B
    __shared__ unsigned int wp2[31 * 32];   // 3968 B: [i][0..15]=wA, [i][16..31]=wB

    const int bc  = blockIdx.x;
    const int c   = bc & (CB - 1);
    const int tid = threadIdx.x;
    const float* __restrict__ xp = x + (size_t)bc * HWp;

    // Fill halo as f16 pairs (zero-padded outside the 64x64 plane).
    for (int idx = tid; idx < 94 * 48; idx += 256) {
        const int r  = idx / 48;
        const int k  = idx - r * 48;
        const int gr = r - PADK, gc = 2 * k - PADK;
        float f0 = 0.f, f1 = 0.f;
        if ((unsigned)gr < 64u) {
            if ((unsigned)gc       < 64u) f0 = xp[gr * 64 + gc];
            if ((unsigned)(gc + 1) < 64u) f1 = xp[gr * 64 + gc + 1];
        }
        xs2[r * 52 + k] = pack2(f0, f1);
    }
    // Dual weight packings.
    const float* __restrict__ wp = dw + (size_t)c * 961;
    for (int idx = tid; idx < 31 * 32; idx += 256) {
        const int i = idx >> 5, s = (idx >> 4) & 1, u = idx & 15;
        float lo, hi;
        if (s == 0) {           // wA[u] = (w[2u], w[2u+1]); u=15 -> (w[30], 0)
            lo = wp[i * 31 + 2 * u];
            hi = (u < 15) ? wp[i * 31 + 2 * u + 1] : 0.f;
        } else {                // wB[u] = u ? (w[2u-1], w[2u]) : (0, w[0])
            lo = u ? wp[i * 31 + 2 * u - 1] : 0.f;
            hi = wp[i * 31 + 2 * u];
        }
        wp2[idx] = pack2(lo, hi);
    }
    __syncthreads();

    const int h     = tid >> 2;          // output row 0..63
    const int kbase = (tid & 3) << 3;    // pair-index base = w0/2
    float acc[16];
#pragma unroll
    for (int t = 0; t < 16; ++t) acc[t] = 0.f;

#pragma unroll 1
    for (int i = 0; i < 31; ++i) {
        uint4 xv[6];                     // 24 aligned pairs: kbase..kbase+23
        const uint4* __restrict__ xsrc =
            reinterpret_cast<const uint4*>(&xs2[(h + i) * 52 + kbase]);
#pragma unroll
        for (int q = 0; q < 6; ++q) xv[q] = xsrc[q];
        const unsigned int* xa = reinterpret_cast<const unsigned int*>(xv);

        {   // even output columns t=2*te
            uint4 wv[4];
            const uint4* wsrc = reinterpret_cast<const uint4*>(&wp2[i * 32]);
#pragma unroll
            for (int q = 0; q < 4; ++q) wv[q] = wsrc[q];
            const unsigned int* wa = reinterpret_cast<const unsigned int*>(wv);
#pragma unroll
            for (int te = 0; te < 8; ++te)
#pragma unroll
                for (int u = 0; u < 16; ++u)
                    acc[2 * te] = dot2(wa[u], xa[te + u], acc[2 * te]);
        }
        {   // odd output columns t=2*to+1
            uint4 wv[4];
            const uint4* wsrc = reinterpret_cast<const uint4*>(&wp2[i * 32 + 16]);
#pragma unroll
            for (int q = 0; q < 4; ++q) wv[q] = wsrc[q];
            const unsigned int* wb = reinterpret_cast<const unsigned int*>(wv);
#pragma unroll
            for (int to = 0; to < 8; ++to)
#pragma unroll
                for (int u = 0; u < 16; ++u)
                    acc[2 * to + 1] = dot2(wb[u], xa[to + u], acc[2 * to + 1]);
        }
    }

    // Store y (fp32, into d_out buffer) — 4x float4, coalesced.
    float* __restrict__ yp = y + (size_t)bc * HWp + h * 64 + (kbase << 1);
#pragma unroll
    for (int q = 0; q < 4; ++q)
        reinterpret_cast<float4*>(yp)[q] = *reinterpret_cast<float4*>(&acc[4 * q]);

    // Per-channel stats: thread partial -> wave shuffle reduce -> one atomic/wave.
    float s = 0.f, s2 = 0.f;
#pragma unroll
    for (int t = 0; t < 16; ++t) { s += acc[t]; s2 = fmaf(acc[t], acc[t], s2); }
#pragma unroll
    for (int off = 32; off > 0; off >>= 1) {
        s  += __shfl_down(s,  off, 64);
        s2 += __shfl_down(s2, off, 64);
    }
    if ((tid & 63) == 0) {
        atomicAdd(&gsum[c],   s);
        atomicAdd(&gsumsq[c], s2);
    }
}

// ---------------------------------------------------------------------------
// Kernel 2a: pw fp32 -> bf16, grid-wide (was a hidden ~100us single-block cost).
// ---------------------------------------------------------------------------
__global__ __launch_bounds__(256) void pwb_kernel(
    const float* __restrict__ pw, __hip_bfloat16* __restrict__ pwb)
{
    const int idx = blockIdx.x * 256 + threadIdx.x;   // 16384 threads x 4 elems
    const float4 v = reinterpret_cast<const float4*>(pw)[idx];
    union { __hip_bfloat16 h[4]; uint2 u; } pk;
    pk.h[0] = __float2bfloat16(v.x); pk.h[1] = __float2bfloat16(v.y);
    pk.h[2] = __float2bfloat16(v.z); pk.h[3] = __float2bfloat16(v.w);
    reinterpret_cast<uint2*>(pwb)[idx] = pk.u;
}

// ---------------------------------------------------------------------------
// Kernel 2b: finalize BN stats -> per-channel scale/shift.
// ---------------------------------------------------------------------------
__global__ __launch_bounds__(256) void stats_kernel(
    const float* __restrict__ gsum, const float* __restrict__ gsumsq,
    const float* __restrict__ gamma, const float* __restrict__ beta,
    float* __restrict__ scale, float* __restrict__ shift)
{
    const int tid = threadIdx.x;
    const float inv = 1.f / 65536.f;
    const float mean = gsum[tid] * inv;
    const float var  = gsumsq[tid] * inv - mean * mean;
    const float sc   = gamma[tid] * rsqrtf(var + 1e-5f);
    scale[tid] = sc;
    shift[tid] = beta[tid] - mean * sc;
}

// ---------------------------------------------------------------------------
// Kernel 3: normalize + ReLU + bf16 + transpose:  y[b][c][p] -> rt[b][p][c]
// ---------------------------------------------------------------------------
__global__ __launch_bounds__(256) void normtrans_kernel(
    const float* __restrict__ y, const float* __restrict__ scale,
    const float* __restrict__ shift, __hip_bfloat16* __restrict__ rt)
{
    __shared__ __hip_bfloat16 tile[32][33];
    const int b   = blockIdx.z;
    const int c0  = blockIdx.y * 32;
    const int p0  = blockIdx.x * 32;
    const int tid = threadIdx.x;

    {   // coalesced read along p
        const int cl  = tid >> 3;
        const int pl4 = (tid & 7) * 4;
        const float4 v = *reinterpret_cast<const float4*>(
            y + (size_t)(b * CB + c0 + cl) * HWp + p0 + pl4);
        const float sc = scale[c0 + cl], sh = shift[c0 + cl];
        tile[cl][pl4 + 0] = __float2bfloat16(fmaxf(fmaf(v.x, sc, sh), 0.f));
        tile[cl][pl4 + 1] = __float2bfloat16(fmaxf(fmaf(v.y, sc, sh), 0.f));
        tile[cl][pl4 + 2] = __float2bfloat16(fmaxf(fmaf(v.z, sc, sh), 0.f));
        tile[cl][pl4 + 3] = __float2bfloat16(fmaxf(fmaf(v.w, sc, sh), 0.f));
    }
    __syncthreads();
    {   // coalesced write along c
        const int pl  = tid >> 3;
        const int cl4 = (tid & 7) * 4;
        union { __hip_bfloat16 h[4]; uint2 u; } pk;
#pragma unroll
        for (int k2 = 0; k2 < 4; ++k2) pk.h[k2] = tile[cl4 + k2][pl];
        *reinterpret_cast<uint2*>(
            rt + ((size_t)b * HWp + p0 + pl) * CB + c0 + cl4) = pk.u;
    }
}

// ---------------------------------------------------------------------------
// Kernel 4: pointwise conv as bf16 MFMA GEMM.
// out[b][o][p] = sum_c pw[o][c] * rt[b][p][c].
// ---------------------------------------------------------------------------
__global__ __launch_bounds__(256, 2) void gemm_kernel(
    const __hip_bfloat16* __restrict__ pwb, const __hip_bfloat16* __restrict__ rt,
    float* __restrict__ out)
{
    __shared__ __hip_bfloat16 ldsA[128 * 32];  // [o-row][c] 64B rows
    __shared__ __hip_bfloat16 ldsB[128 * 32];  // [p-row][c] 64B rows

    const int tid  = threadIdx.x;
    const int lane = tid & 63;
    const int wid  = tid >> 6;
    const int b    = blockIdx.z;
    const int m0   = blockIdx.y * 128;
    const int p0   = blockIdx.x * 128;
    const int wm   = wid >> 1, wn = wid & 1;

    f32x4 acc[4][4];
#pragma unroll
    for (int mi = 0; mi < 4; ++mi)
#pragma unroll
        for (int ni = 0; ni < 4; ++ni) acc[mi][ni] = {0.f, 0.f, 0.f, 0.f};

    const int srow = lane >> 2;
    const int scol = (lane & 3) * 8;
    const int fr   = lane & 15;
    const int fk   = (lane >> 4) * 8;

    const size_t rtbase = (size_t)b * HWp;

    for (int ks = 0; ks < 8; ++ks) {
        const int k0 = ks * 32;
#pragma unroll
        for (int q = 0; q < 2; ++q) {
            const int issue = wid * 2 + q;
            const int row   = issue * 16 + srow;
            const __hip_bfloat16* gA = pwb + (size_t)(m0 + row) * CB + k0 + scol;
            const __hip_bfloat16* gB = rt + (rtbase + p0 + row) * CB + k0 + scol;
            __builtin_amdgcn_global_load_lds((gvoid*)gA, (svoid*)(ldsA + issue * 512), 16, 0, 0);
            __builtin_amdgcn_global_load_lds((gvoid*)gB, (svoid*)(ldsB + issue * 512), 16, 0, 0);
        }
        __syncthreads();

        bf16x8 af[4], bfr[4];
#pragma unroll
        for (int mi = 0; mi < 4; ++mi)
            af[mi] = *reinterpret_cast<const bf16x8*>(
                ldsA + (wm * 64 + mi * 16 + fr) * 32 + fk);
#pragma unroll
        for (int ni = 0; ni < 4; ++ni)
            bfr[ni] = *reinterpret_cast<const bf16x8*>(
                ldsB + (wn * 64 + ni * 16 + fr) * 32 + fk);

#pragma unroll
        for (int mi = 0; mi < 4; ++mi)
#pragma unroll
            for (int ni = 0; ni < 4; ++ni)
                acc[mi][ni] = __builtin_amdgcn_mfma_f32_16x16x32_bf16(
                    af[mi], bfr[ni], acc[mi][ni], 0, 0, 0);
        __syncthreads();
    }

    const int frow = (lane >> 4) * 4;
#pragma unroll
    for (int mi = 0; mi < 4; ++mi)
#pragma unroll
        for (int ni = 0; ni < 4; ++ni)
#pragma unroll
            for (int v = 0; v < 4; ++v) {
                const int o = m0 + wm * 64 + mi * 16 + frow + v;
                const int p = p0 + wn * 64 + ni * 16 + fr;
                out[((size_t)(b * CB + o)) * HWp + p] = acc[mi][ni][v];
            }
}

// ---------------------------------------------------------------------------
extern "C" void kernel_launch(void* const* d_in, const int* in_sizes, int n_in,
                              void* d_out, int out_size, void* d_ws, size_t ws_size,
                              hipStream_t stream) {
    (void)in_sizes; (void)n_in; (void)out_size; (void)ws_size;
    const float* x     = (const float*)d_in[0];
    const float* dw    = (const float*)d_in[1];
    const float* gamma = (const float*)d_in[2];
    const float* beta  = (const float*)d_in[3];
    const float* pw    = (const float*)d_in[4];
    float* out = (float*)d_out;

    // Workspace: rt (32 MB) | gsum | gsumsq | scale | shift | pwb (128 KB)
    char* ws = (char*)d_ws;
    __hip_bfloat16* rt = (__hip_bfloat16*)ws;
    float* gsum   = (float*)(ws + (size_t)33554432);
    float* gsumsq = gsum + 256;
    float* scale  = gsum + 512;
    float* shift  = gsum + 768;
    __hip_bfloat16* pwb = (__hip_bfloat16*)(ws + (size_t)33554432 + 4096);

    hipMemsetAsync(gsum, 0, 2048, stream);

    // y (fp32) lives in d_out; GEMM overwrites it at the end.
    pwb_kernel<<<dim3(64), 256, 0, stream>>>(pw, pwb);
    dwconv_kernel<<<dim3(NB * CB), 256, 0, stream>>>(x, dw, out, gsum, gsumsq);
    stats_kernel<<<dim3(1), 256, 0, stream>>>(gsum, gsumsq, gamma, beta, scale, shift);
    normtrans_kernel<<<dim3(128, 8, NB), 256, 0, stream>>>(out, scale, shift, rt);
    gemm_kernel<<<dim3(32, 2, NB), 256, 0, stream>>>(pwb, rt, out);
}

// Round 3
// 243.615 us; speedup vs baseline: 2.3320x; 1.6457x over previous
//
#include <hip/hip_runtime.h>
#include <hip/hip_bf16.h>

namespace {
constexpr int CB   = 256;   // channels
constexpr int HWp  = 4096;  // 64*64 pixels per plane
constexpr int NB   = 16;    // batch

typedef __bf16    bf16x8 __attribute__((ext_vector_type(8)));
typedef float     f32x4  __attribute__((ext_vector_type(4)));
typedef float     f32x16 __attribute__((ext_vector_type(16)));
typedef _Float16  f16x2  __attribute__((ext_vector_type(2)));
typedef _Float16  f16x8  __attribute__((ext_vector_type(8)));

typedef __attribute__((address_space(1))) void gvoid;  // global
typedef __attribute__((address_space(3))) void svoid;  // LDS

__device__ __forceinline__ unsigned int pack2(float lo, float hi) {
#if __has_builtin(__builtin_amdgcn_cvt_pkrtz)
    return __builtin_bit_cast(unsigned int, __builtin_amdgcn_cvt_pkrtz(lo, hi));
#else
    f16x2 v; v[0] = (_Float16)lo; v[1] = (_Float16)hi;
    return __builtin_bit_cast(unsigned int, v);
#endif
}

// Toeplitz table geometry: entry = one A-fragment lane (8 f16 = 16B).
// index = ((c*31 + r)*4 + kq)*64 + lane
constexpr int TOEP_PER_C = 31 * 4 * 64;   // uint4 entries per channel
}

// ---------------------------------------------------------------------------
// Kernel 0: build per-channel Toeplitz A-fragments for mfma_f32_32x32x16_f16.
// A[i,k] = w[r][k-i-1] for 0<=k-i-1<=30 else 0;  lane l: i=l&31, k=(l>>5)*8+e,
// global k = kq*16 + (l>>5)*8 + e.  7936 blocks x 256 thr, one entry/thread.
// ---------------------------------------------------------------------------
__global__ __launch_bounds__(256) void toep_kernel(
    const float* __restrict__ dw, uint4* __restrict__ toep)
{
    const int flat = blockIdx.x * 256 + threadIdx.x;      // < 256*31*4*64
    const int lane = flat & 63;
    const int kq   = (flat >> 6) & 3;
    const int rc   = flat >> 8;                           // c*31 + r
    const int r    = rc % 31;
    const int c    = rc / 31;
    const int i    = lane & 31;
    const int kbase = kq * 16 + (lane >> 5) * 8;

    const float* __restrict__ wr = dw + (size_t)c * 961 + r * 31;
    union { _Float16 h[8]; uint4 u; } out;
#pragma unroll
    for (int e = 0; e < 8; ++e) {
        const int t = kbase + e - i - 1;
        out.h[e] = (t >= 0 && t <= 30) ? (_Float16)wr[t] : (_Float16)0.f;
    }
    toep[flat] = out.u;
}

// ---------------------------------------------------------------------------
// Kernel 1: depthwise 31x31 conv via MFMA (f16 in, fp32 acc) + BN partials.
// One block per (b,c) plane, 4 waves; wave w owns output rows [16w,16w+16).
// Halo in LDS as f16: 94 rows x 104-f16 stride (208 B). Output tile per wave:
// C[i,j] 32x32 = (w-offset i) x (j: h_sub=j>>1, w_block=(j&1)*32).
// Per r (31 kernel rows) x kq (4 K-chunks): A-frag from global Toeplitz
// (L2-resident), B-frag = ds_read_b128 from halo, 1 MFMA. 124 MFMA/wave.
// ---------------------------------------------------------------------------
__global__ __launch_bounds__(256, 5) void dwconv_kernel(
    const float* __restrict__ x, const uint4* __restrict__ toep,
    float* __restrict__ y, float* __restrict__ gsum, float* __restrict__ gsumsq)
{
    __shared__ unsigned int xs[94 * 52];   // f16 pairs; row stride 52 u32 = 208B

    const int bc  = blockIdx.x;
    const int c   = bc & (CB - 1);
    const int tid = threadIdx.x;
    const float* __restrict__ xp = x + (size_t)bc * HWp;

    // Zero the full halo (1222 uint4), then fill interior rows 15..78.
    for (int idx = tid; idx < 1222; idx += 256)
        reinterpret_cast<uint4*>(xs)[idx] = uint4{0, 0, 0, 0};
    __syncthreads();
    {
        const int row = tid >> 2;          // 0..63
        const int q   = tid & 3;           // 16-float chunk
        const float4* src = reinterpret_cast<const float4*>(xp + row * 64 + q * 16);
        float4 v0 = src[0], v1 = src[1], v2 = src[2], v3 = src[3];
        uint4 p0, p1;
        p0.x = pack2(v0.x, v0.y); p0.y = pack2(v0.z, v0.w);
        p0.z = pack2(v1.x, v1.y); p0.w = pack2(v1.z, v1.w);
        p1.x = pack2(v2.x, v2.y); p1.y = pack2(v2.z, v2.w);
        p1.z = pack2(v3.x, v3.y); p1.w = pack2(v3.z, v3.w);
        uint4* dst = reinterpret_cast<uint4*>(&xs[(row + 15) * 52 + 8 + q * 8]);
        dst[0] = p0; dst[1] = p1;
    }
    __syncthreads();

    const int lane = tid & 63;
    const int wid  = tid >> 6;
    const int h0   = wid * 16;
    const int j    = lane & 31;
    const int half = lane >> 5;

    // B-frag base: row = h0 + (j>>1) + r, u32 col = (j&1)*16 + kq*8 + half*4
    const unsigned int* __restrict__ xb =
        &xs[(h0 + (j >> 1)) * 52 + (j & 1) * 16 + half * 4];
    const uint4* __restrict__ tp = toep + (size_t)c * TOEP_PER_C + lane;

    f32x16 acc = {};

    uint4 afA[4]; f16x8 bfA[4];
#pragma unroll
    for (int kq = 0; kq < 4; ++kq) {
        afA[kq] = tp[kq * 64];
        bfA[kq] = *reinterpret_cast<const f16x8*>(xb + kq * 8);
    }
#pragma unroll 2
    for (int r = 0; r < 31; ++r) {
        uint4 afB[4]; f16x8 bfB[4];
        if (r < 30) {
            const unsigned int* xr = xb + (r + 1) * 52;
#pragma unroll
            for (int kq = 0; kq < 4; ++kq) {
                afB[kq] = tp[((r + 1) * 4 + kq) * 64];
                bfB[kq] = *reinterpret_cast<const f16x8*>(xr + kq * 8);
            }
        }
#pragma unroll
        for (int kq = 0; kq < 4; ++kq)
            acc = __builtin_amdgcn_mfma_f32_32x32x16_f16(
                __builtin_bit_cast(f16x8, afA[kq]), bfA[kq], acc, 0, 0, 0);
#pragma unroll
        for (int kq = 0; kq < 4; ++kq) { afA[kq] = afB[kq]; bfA[kq] = bfB[kq]; }
    }

    // D layout (32x32): col j = lane&31, row i = (reg&3) + 8*(reg>>2) + 4*half.
    // Output: h = h0 + (j>>1), w = (j&1)*32 + i.  4x float4 stores (g=reg>>2).
    const int hout = h0 + (j >> 1);
    float* __restrict__ yp = y + (size_t)bc * HWp + hout * 64 + (j & 1) * 32 + 4 * half;
#pragma unroll
    for (int g = 0; g < 4; ++g) {
        f32x4 v = { acc[4 * g + 0], acc[4 * g + 1], acc[4 * g + 2], acc[4 * g + 3] };
        *reinterpret_cast<f32x4*>(yp + 8 * g) = v;
    }

    // BN partials: each lane sums its 16 outputs -> wave reduce -> atomic.
    float s = 0.f, s2 = 0.f;
#pragma unroll
    for (int t = 0; t < 16; ++t) { s += acc[t]; s2 = fmaf(acc[t], acc[t], s2); }
#pragma unroll
    for (int off = 32; off > 0; off >>= 1) {
        s  += __shfl_down(s,  off, 64);
        s2 += __shfl_down(s2, off, 64);
    }
    if (lane == 0) {
        atomicAdd(&gsum[c],   s);
        atomicAdd(&gsumsq[c], s2);
    }
}

// ---------------------------------------------------------------------------
// Kernel 2a: pw fp32 -> bf16 (grid-wide).
// ---------------------------------------------------------------------------
__global__ __launch_bounds__(256) void pwb_kernel(
    const float* __restrict__ pw, __hip_bfloat16* __restrict__ pwb)
{
    const int idx = blockIdx.x * 256 + threadIdx.x;
    const float4 v = reinterpret_cast<const float4*>(pw)[idx];
    union { __hip_bfloat16 h[4]; uint2 u; } pk;
    pk.h[0] = __float2bfloat16(v.x); pk.h[1] = __float2bfloat16(v.y);
    pk.h[2] = __float2bfloat16(v.z); pk.h[3] = __float2bfloat16(v.w);
    reinterpret_cast<uint2*>(pwb)[idx] = pk.u;
}

// ---------------------------------------------------------------------------
// Kernel 2b: finalize BN stats -> per-channel scale/shift.
// ---------------------------------------------------------------------------
__global__ __launch_bounds__(256) void stats_kernel(
    const float* __restrict__ gsum, const float* __restrict__ gsumsq,
    const float* __restrict__ gamma, const float* __restrict__ beta,
    float* __restrict__ scale, float* __restrict__ shift)
{
    const int tid = threadIdx.x;
    const float inv = 1.f / 65536.f;
    const float mean = gsum[tid] * inv;
    const float var  = gsumsq[tid] * inv - mean * mean;
    const float sc   = gamma[tid] * rsqrtf(var + 1e-5f);
    scale[tid] = sc;
    shift[tid] = beta[tid] - mean * sc;
}

// ---------------------------------------------------------------------------
// Kernel 3: normalize + ReLU + bf16 + transpose:  y[b][c][p] -> rt[b][p][c]
// ---------------------------------------------------------------------------
__global__ __launch_bounds__(256) void normtrans_kernel(
    const float* __restrict__ y, const float* __restrict__ scale,
    const float* __restrict__ shift, __hip_bfloat16* __restrict__ rt)
{
    __shared__ __hip_bfloat16 tile[32][33];
    const int b   = blockIdx.z;
    const int c0  = blockIdx.y * 32;
    const int p0  = blockIdx.x * 32;
    const int tid = threadIdx.x;

    {   // coalesced read along p
        const int cl  = tid >> 3;
        const int pl4 = (tid & 7) * 4;
        const float4 v = *reinterpret_cast<const float4*>(
            y + (size_t)(b * CB + c0 + cl) * HWp + p0 + pl4);
        const float sc = scale[c0 + cl], sh = shift[c0 + cl];
        tile[cl][pl4 + 0] = __float2bfloat16(fmaxf(fmaf(v.x, sc, sh), 0.f));
        tile[cl][pl4 + 1] = __float2bfloat16(fmaxf(fmaf(v.y, sc, sh), 0.f));
        tile[cl][pl4 + 2] = __float2bfloat16(fmaxf(fmaf(v.z, sc, sh), 0.f));
        tile[cl][pl4 + 3] = __float2bfloat16(fmaxf(fmaf(v.w, sc, sh), 0.f));
    }
    __syncthreads();
    {   // coalesced write along c
        const int pl  = tid >> 3;
        const int cl4 = (tid & 7) * 4;
        union { __hip_bfloat16 h[4]; uint2 u; } pk;
#pragma unroll
        for (int k2 = 0; k2 < 4; ++k2) pk.h[k2] = tile[cl4 + k2][pl];
        *reinterpret_cast<uint2*>(
            rt + ((size_t)b * HWp + p0 + pl) * CB + c0 + cl4) = pk.u;
    }
}

// ---------------------------------------------------------------------------
// Kernel 4: pointwise conv as bf16 MFMA GEMM.
// out[b][o][p] = sum_c pw[o][c] * rt[b][p][c].
// ---------------------------------------------------------------------------
__global__ __launch_bounds__(256, 2) void gemm_kernel(
    const __hip_bfloat16* __restrict__ pwb, const __hip_bfloat16* __restrict__ rt,
    float* __restrict__ out)
{
    __shared__ __hip_bfloat16 ldsA[128 * 32];  // [o-row][c] 64B rows
    __shared__ __hip_bfloat16 ldsB[128 * 32];  // [p-row][c] 64B rows

    const int tid  = threadIdx.x;
    const int lane = tid & 63;
    const int wid  = tid >> 6;
    const int b    = blockIdx.z;
    const int m0   = blockIdx.y * 128;
    const int p0   = blockIdx.x * 128;
    const int wm   = wid >> 1, wn = wid & 1;

    f32x4 acc[4][4];
#pragma unroll
    for (int mi = 0; mi < 4; ++mi)
#pragma unroll
        for (int ni = 0; ni < 4; ++ni) acc[mi][ni] = {0.f, 0.f, 0.f, 0.f};

    const int srow = lane >> 2;
    const int scol = (lane & 3) * 8;
    const int fr   = lane & 15;
    const int fk   = (lane >> 4) * 8;

    const size_t rtbase = (size_t)b * HWp;

    for (int ks = 0; ks < 8; ++ks) {
        const int k0 = ks * 32;
#pragma unroll
        for (int q = 0; q < 2; ++q) {
            const int issue = wid * 2 + q;
            const int row   = issue * 16 + srow;
            const __hip_bfloat16* gA = pwb + (size_t)(m0 + row) * CB + k0 + scol;
            const __hip_bfloat16* gB = rt + (rtbase + p0 + row) * CB + k0 + scol;
            __builtin_amdgcn_global_load_lds((gvoid*)gA, (svoid*)(ldsA + issue * 512), 16, 0, 0);
            __builtin_amdgcn_global_load_lds((gvoid*)gB, (svoid*)(ldsB + issue * 512), 16, 0, 0);
        }
        __syncthreads();

        bf16x8 af[4], bfr[4];
#pragma unroll
        for (int mi = 0; mi < 4; ++mi)
            af[mi] = *reinterpret_cast<const bf16x8*>(
                ldsA + (wm * 64 + mi * 16 + fr) * 32 + fk);
#pragma unroll
        for (int ni = 0; ni < 4; ++ni)
            bfr[ni] = *reinterpret_cast<const bf16x8*>(
                ldsB + (wn * 64 + ni * 16 + fr) * 32 + fk);

#pragma unroll
        for (int mi = 0; mi < 4; ++mi)
#pragma unroll
            for (int ni = 0; ni < 4; ++ni)
                acc[mi][ni] = __builtin_amdgcn_mfma_f32_16x16x32_bf16(
                    af[mi], bfr[ni], acc[mi][ni], 0, 0, 0);
        __syncthreads();
    }

    const int frow = (lane >> 4) * 4;
#pragma unroll
    for (int mi = 0; mi < 4; ++mi)
#pragma unroll
        for (int ni = 0; ni < 4; ++ni)
#pragma unroll
            for (int v = 0; v < 4; ++v) {
                const int o = m0 + wm * 64 + mi * 16 + frow + v;
                const int p = p0 + wn * 64 + ni * 16 + fr;
                out[((size_t)(b * CB + o)) * HWp + p] = acc[mi][ni][v];
            }
}

// ---------------------------------------------------------------------------
extern "C" void kernel_launch(void* const* d_in, const int* in_sizes, int n_in,
                              void* d_out, int out_size, void* d_ws, size_t ws_size,
                              hipStream_t stream) {
    (void)in_sizes; (void)n_in; (void)out_size; (void)ws_size;
    const float* x     = (const float*)d_in[0];
    const float* dw    = (const float*)d_in[1];
    const float* gamma = (const float*)d_in[2];
    const float* beta  = (const float*)d_in[3];
    const float* pw    = (const float*)d_in[4];
    float* out = (float*)d_out;

    // Workspace: [0,33.5MB) shared by toep (32.5MB, dies after dwconv) then
    // rt (32MB, born at normtrans) | gsum | gsumsq | scale | shift | pwb.
    char* ws = (char*)d_ws;
    uint4* toep        = (uint4*)ws;
    __hip_bfloat16* rt = (__hip_bfloat16*)ws;
    float* gsum   = (float*)(ws + (size_t)33554432);
    float* gsumsq = gsum + 256;
    float* scale  = gsum + 512;
    float* shift  = gsum + 768;
    __hip_bfloat16* pwb = (__hip_bfloat16*)(ws + (size_t)33554432 + 4096);

    hipMemsetAsync(gsum, 0, 2048, stream);

    pwb_kernel<<<dim3(64), 256, 0, stream>>>(pw, pwb);
    toep_kernel<<<dim3(7936), 256, 0, stream>>>(dw, toep);
    // y (fp32) lives in d_out; GEMM overwrites it at the end.
    dwconv_kernel<<<dim3(NB * CB), 256, 0, stream>>>(x, toep, out, gsum, gsumsq);
    stats_kernel<<<dim3(1), 256, 0, stream>>>(gsum, gsumsq, gamma, beta, scale, shift);
    normtrans_kernel<<<dim3(128, 8, NB), 256, 0, stream>>>(out, scale, shift, rt);
    gemm_kernel<<<dim3(32, 2, NB), 256, 0, stream>>>(pwb, rt, out);
}

// Round 4
// 219.757 us; speedup vs baseline: 2.5852x; 1.1086x over previous
//
#include <hip/hip_runtime.h>
#include <hip/hip_bf16.h>

namespace {
constexpr int CB   = 256;   // channels
constexpr int HWp  = 4096;  // 64*64 pixels per plane
constexpr int NB   = 16;    // batch

typedef __bf16    bf16x8 __attribute__((ext_vector_type(8)));
typedef float     f32x4  __attribute__((ext_vector_type(4)));
typedef float     f32x16 __attribute__((ext_vector_type(16)));
typedef _Float16  f16x2  __attribute__((ext_vector_type(2)));
typedef _Float16  f16x8  __attribute__((ext_vector_type(8)));

typedef __attribute__((address_space(1))) void gvoid;  // global
typedef __attribute__((address_space(3))) void svoid;  // LDS

__device__ __forceinline__ unsigned int pack2(float lo, float hi) {
#if __has_builtin(__builtin_amdgcn_cvt_pkrtz)
    return __builtin_bit_cast(unsigned int, __builtin_amdgcn_cvt_pkrtz(lo, hi));
#else
    f16x2 v; v[0] = (_Float16)lo; v[1] = (_Float16)hi;
    return __builtin_bit_cast(unsigned int, v);
#endif
}

// Toeplitz table: entry = one A-fragment lane (8 f16 = 16B).
// index = ((c*31 + r)*4 + kq)*64 + lane
constexpr int TOEP_PER_C = 31 * 4 * 64;
constexpr int HALO_U32   = 94 * 64;      // per-image halo, stride 64 u32, swizzled
}

// ---------------------------------------------------------------------------
// Kernel 0: prep = pw fp32->bf16 (blocks 0..63) + Toeplitz A-frag build
// (blocks 64..7999).  A[i,k] = w[r][k-i-1] for 0<=k-i-1<=30 else 0.
// ---------------------------------------------------------------------------
__global__ __launch_bounds__(256) void prep_kernel(
    const float* __restrict__ pw, __hip_bfloat16* __restrict__ pwb,
    const float* __restrict__ dw, uint4* __restrict__ toep)
{
    const int bid = blockIdx.x;
    const int tid = threadIdx.x;
    if (bid < 64) {
        const int idx = bid * 256 + tid;
        const float4 v = reinterpret_cast<const float4*>(pw)[idx];
        union { __hip_bfloat16 h[4]; uint2 u; } pk;
        pk.h[0] = __float2bfloat16(v.x); pk.h[1] = __float2bfloat16(v.y);
        pk.h[2] = __float2bfloat16(v.z); pk.h[3] = __float2bfloat16(v.w);
        reinterpret_cast<uint2*>(pwb)[idx] = pk.u;
        return;
    }
    const int flat = (bid - 64) * 256 + tid;              // < 256*31*4*64
    const int lane = flat & 63;
    const int kq   = (flat >> 6) & 3;
    const int rc   = flat >> 8;                           // c*31 + r
    const int r    = rc % 31;
    const int c    = rc / 31;
    const int i    = lane & 31;
    const int kbase = kq * 16 + (lane >> 5) * 8;

    const float* __restrict__ wr = dw + (size_t)c * 961 + r * 31;
    union { _Float16 h[8]; uint4 u; } out;
#pragma unroll
    for (int e = 0; e < 8; ++e) {
        const int t = kbase + e - i - 1;
        out.h[e] = (t >= 0 && t <= 30) ? (_Float16)wr[t] : (_Float16)0.f;
    }
    toep[flat] = out.u;
}

// ---------------------------------------------------------------------------
// Kernel 1: depthwise 31x31 conv via MFMA, TWO images per block (same c) so
// each Toeplitz A-load feeds 2 MFMAs.  Halo per image: 94 rows x 64 u32
// (f16 pairs), XOR-swizzled (col ^= (row&7)<<2 within the row) so the
// B-frag ds_read_b128 pattern is bank-uniform (8-cyc floor).
// Wave w: output rows [16w,16w+16) of both images; C[i,j] 32x32 per image:
// i = w-offset, j = (h_sub, w_block).  y written as f16.
// ---------------------------------------------------------------------------
__global__ __launch_bounds__(256, 3) void dwconv_kernel(
    const float* __restrict__ x, const uint4* __restrict__ toep,
    _Float16* __restrict__ y16, float* __restrict__ gsum, float* __restrict__ gsumsq)
{
    __shared__ unsigned int xs[2 * HALO_U32];   // 48128 B

    const int bid = blockIdx.x;           // bp*256 + c  (c in low bits -> XCD = c%8)
    const int c   = bid & 255;
    const int bp  = bid >> 8;
    const int tid = threadIdx.x;

    // Zero both halos (covers pad + swizzle spill region).
    for (int idx = tid; idx < 2 * HALO_U32 / 4; idx += 256)
        reinterpret_cast<uint4*>(xs)[idx] = uint4{0, 0, 0, 0};
    __syncthreads();

    // Interior fill, both images: row tid>>2, 16-float chunk tid&3.
    {
        const int row = tid >> 2;          // 0..63
        const int q   = tid & 3;
        const int hr  = row + 15;
        const int swz = (hr & 7) << 2;
        const int p0  = (8  + q * 8) ^ swz;
        const int p1  = (12 + q * 8) ^ swz;
#pragma unroll
        for (int img = 0; img < 2; ++img) {
            const float4* src = reinterpret_cast<const float4*>(
                x + ((size_t)((bp * 2 + img) * CB + c)) * HWp + row * 64 + q * 16);
            float4 v0 = src[0], v1 = src[1], v2 = src[2], v3 = src[3];
            uint4 a, b;
            a.x = pack2(v0.x, v0.y); a.y = pack2(v0.z, v0.w);
            a.z = pack2(v1.x, v1.y); a.w = pack2(v1.z, v1.w);
            b.x = pack2(v2.x, v2.y); b.y = pack2(v2.z, v2.w);
            b.z = pack2(v3.x, v3.y); b.w = pack2(v3.z, v3.w);
            unsigned int* base = xs + img * HALO_U32 + hr * 64;
            *reinterpret_cast<uint4*>(base + p0) = a;
            *reinterpret_cast<uint4*>(base + p1) = b;
        }
    }
    __syncthreads();

    const int lane = tid & 63;
    const int wid  = tid >> 6;
    const int j    = lane & 31;
    const int half = lane >> 5;
    const int rowb = wid * 16 + (j >> 1);          // base halo row / output h
    const int colb = (j & 1) * 16 + half * 4;      // logical u32 col base
    const uint4* __restrict__ tp = toep + (size_t)c * TOEP_PER_C + lane;

    f32x16 acc0 = {}, acc1 = {};
    uint4 afA[4];
#pragma unroll
    for (int kq = 0; kq < 4; ++kq) afA[kq] = tp[kq * 64];

#pragma unroll 1
    for (int r = 0; r < 31; ++r) {
        uint4 afB[4];
        if (r < 30) {
#pragma unroll
            for (int kq = 0; kq < 4; ++kq) afB[kq] = tp[((r + 1) * 4 + kq) * 64];
        }
        const int row = rowb + r;
        const int swz = (row & 7) << 2;
        const unsigned int* __restrict__ xr = xs + row * 64;
        f16x8 b0[4], b1[4];
#pragma unroll
        for (int kq = 0; kq < 4; ++kq) {
            const int p = (colb + kq * 8) ^ swz;
            b0[kq] = *reinterpret_cast<const f16x8*>(xr + p);
            b1[kq] = *reinterpret_cast<const f16x8*>(xr + HALO_U32 + p);
        }
#pragma unroll
        for (int kq = 0; kq < 4; ++kq)
            acc0 = __builtin_amdgcn_mfma_f32_32x32x16_f16(
                __builtin_bit_cast(f16x8, afA[kq]), b0[kq], acc0, 0, 0, 0);
#pragma unroll
        for (int kq = 0; kq < 4; ++kq)
            acc1 = __builtin_amdgcn_mfma_f32_32x32x16_f16(
                __builtin_bit_cast(f16x8, afA[kq]), b1[kq], acc1, 0, 0, 0);
        if (r < 30) {
#pragma unroll
            for (int kq = 0; kq < 4; ++kq) afA[kq] = afB[kq];
        }
    }

    // Store y as f16.  D layout: col j = lane&31 -> (h_sub, w_block);
    // row i = (reg&3) + 8*(reg>>2) + 4*half -> w offset.
    const size_t pl0 = ((size_t)(bp * 2 * CB + c)) * HWp + rowb * 64 + (j & 1) * 32 + 4 * half;
#pragma unroll
    for (int g = 0; g < 4; ++g) {
        uint2 u0, u1;
        u0.x = pack2(acc0[4 * g + 0], acc0[4 * g + 1]);
        u0.y = pack2(acc0[4 * g + 2], acc0[4 * g + 3]);
        u1.x = pack2(acc1[4 * g + 0], acc1[4 * g + 1]);
        u1.y = pack2(acc1[4 * g + 2], acc1[4 * g + 3]);
        *reinterpret_cast<uint2*>(y16 + pl0 + 8 * g)            = u0;
        *reinterpret_cast<uint2*>(y16 + pl0 + CB * HWp + 8 * g) = u1;
    }

    // BN partials over both images (fp32 accs, exact).
    float s = 0.f, s2 = 0.f;
#pragma unroll
    for (int t = 0; t < 16; ++t) {
        s += acc0[t] + acc1[t];
        s2 = fmaf(acc0[t], acc0[t], s2);
        s2 = fmaf(acc1[t], acc1[t], s2);
    }
#pragma unroll
    for (int off = 32; off > 0; off >>= 1) {
        s  += __shfl_down(s,  off, 64);
        s2 += __shfl_down(s2, off, 64);
    }
    if (lane == 0) {
        atomicAdd(&gsum[c],   s);
        atomicAdd(&gsumsq[c], s2);
    }
}

// ---------------------------------------------------------------------------
// Kernel 2: stats finalize (per block, 32 ch) + normalize + ReLU + bf16 +
// transpose y16[b][c][p] -> rt[b][p][c].  Tile 32c x 64p.
// ---------------------------------------------------------------------------
__global__ __launch_bounds__(256) void normtrans_kernel(
    const _Float16* __restrict__ y16,
    const float* __restrict__ gsum, const float* __restrict__ gsumsq,
    const float* __restrict__ gamma, const float* __restrict__ beta,
    __hip_bfloat16* __restrict__ rt)
{
    __shared__ __hip_bfloat16 tile[32 * 72];   // stride 72 f16 (144B, 16B-aligned)
    __shared__ float scsh[64];
    const int b   = blockIdx.z;
    const int c0  = blockIdx.y * 32;
    const int p0  = blockIdx.x * 64;
    const int tid = threadIdx.x;

    const int cl  = tid >> 3;
    const int pl8 = (tid & 7) * 8;
    // Issue y read early; overlap with stats finalize.
    const uint4 raw = *reinterpret_cast<const uint4*>(
        y16 + ((size_t)(b * CB + c0 + cl)) * HWp + p0 + pl8);
    if (tid < 32) {
        const int cc = c0 + tid;
        const float inv = 1.f / 65536.f;
        const float mean = gsum[cc] * inv;
        const float var  = gsumsq[cc] * inv - mean * mean;
        const float sc   = gamma[cc] * rsqrtf(var + 1e-5f);
        scsh[tid]      = sc;
        scsh[32 + tid] = beta[cc] - mean * sc;
    }
    __syncthreads();
    {
        const float sc = scsh[cl], sh = scsh[32 + cl];
        const f16x8 hv = __builtin_bit_cast(f16x8, raw);
        union { __hip_bfloat16 h[8]; uint4 u; } o;
#pragma unroll
        for (int e = 0; e < 8; ++e)
            o.h[e] = __float2bfloat16(fmaxf(fmaf((float)hv[e], sc, sh), 0.f));
        *reinterpret_cast<uint4*>(&tile[cl * 72 + pl8]) = o.u;
    }
    __syncthreads();
    {
        const int pl  = tid >> 2;
        const int cl8 = (tid & 3) * 8;
        union { __hip_bfloat16 h[8]; uint4 u; } o;
#pragma unroll
        for (int e = 0; e < 8; ++e) o.h[e] = tile[(cl8 + e) * 72 + pl];
        *reinterpret_cast<uint4*>(
            rt + ((size_t)b * HWp + p0 + pl) * CB + c0 + cl8) = o.u;
    }
}

// ---------------------------------------------------------------------------
// Kernel 3: pointwise conv as bf16 MFMA GEMM.
// out[b][o][p] = sum_c pw[o][c] * rt[b][p][c].
// ---------------------------------------------------------------------------
__global__ __launch_bounds__(256, 2) void gemm_kernel(
    const __hip_bfloat16* __restrict__ pwb, const __hip_bfloat16* __restrict__ rt,
    float* __restrict__ out)
{
    __shared__ __hip_bfloat16 ldsA[128 * 32];  // [o-row][c] 64B rows
    __shared__ __hip_bfloat16 ldsB[128 * 32];  // [p-row][c] 64B rows

    const int tid  = threadIdx.x;
    const int lane = tid & 63;
    const int wid  = tid >> 6;
    const int b    = blockIdx.z;
    const int m0   = blockIdx.y * 128;
    const int p0   = blockIdx.x * 128;
    const int wm   = wid >> 1, wn = wid & 1;

    f32x4 acc[4][4];
#pragma unroll
    for (int mi = 0; mi < 4; ++mi)
#pragma unroll
        for (int ni = 0; ni < 4; ++ni) acc[mi][ni] = {0.f, 0.f, 0.f, 0.f};

    const int srow = lane >> 2;
    const int scol = (lane & 3) * 8;
    const int fr   = lane & 15;
    const int fk   = (lane >> 4) * 8;

    const size_t rtbase = (size_t)b * HWp;

    for (int ks = 0; ks < 8; ++ks) {
        const int k0 = ks * 32;
#pragma unroll
        for (int q = 0; q < 2; ++q) {
            const int issue = wid * 2 + q;
            const int row   = issue * 16 + srow;
            const __hip_bfloat16* gA = pwb + (size_t)(m0 + row) * CB + k0 + scol;
            const __hip_bfloat16* gB = rt + (rtbase + p0 + row) * CB + k0 + scol;
            __builtin_amdgcn_global_load_lds((gvoid*)gA, (svoid*)(ldsA + issue * 512), 16, 0, 0);
            __builtin_amdgcn_global_load_lds((gvoid*)gB, (svoid*)(ldsB + issue * 512), 16, 0, 0);
        }
        __syncthreads();

        bf16x8 af[4], bfr[4];
#pragma unroll
        for (int mi = 0; mi < 4; ++mi)
            af[mi] = *reinterpret_cast<const bf16x8*>(
                ldsA + (wm * 64 + mi * 16 + fr) * 32 + fk);
#pragma unroll
        for (int ni = 0; ni < 4; ++ni)
            bfr[ni] = *reinterpret_cast<const bf16x8*>(
                ldsB + (wn * 64 + ni * 16 + fr) * 32 + fk);

#pragma unroll
        for (int mi = 0; mi < 4; ++mi)
#pragma unroll
            for (int ni = 0; ni < 4; ++ni)
                acc[mi][ni] = __builtin_amdgcn_mfma_f32_16x16x32_bf16(
                    af[mi], bfr[ni], acc[mi][ni], 0, 0, 0);
        __syncthreads();
    }

    const int frow = (lane >> 4) * 4;
#pragma unroll
    for (int mi = 0; mi < 4; ++mi)
#pragma unroll
        for (int ni = 0; ni < 4; ++ni)
#pragma unroll
            for (int v = 0; v < 4; ++v) {
                const int o = m0 + wm * 64 + mi * 16 + frow + v;
                const int p = p0 + wn * 64 + ni * 16 + fr;
                out[((size_t)(b * CB + o)) * HWp + p] = acc[mi][ni][v];
            }
}

// ---------------------------------------------------------------------------
extern "C" void kernel_launch(void* const* d_in, const int* in_sizes, int n_in,
                              void* d_out, int out_size, void* d_ws, size_t ws_size,
                              hipStream_t stream) {
    (void)in_sizes; (void)n_in; (void)out_size; (void)ws_size;
    const float* x     = (const float*)d_in[0];
    const float* dw    = (const float*)d_in[1];
    const float* gamma = (const float*)d_in[2];
    const float* beta  = (const float*)d_in[3];
    const float* pw    = (const float*)d_in[4];
    float* out = (float*)d_out;

    // ws: [0,32MiB) toep (dies after dwconv) then rt (born at normtrans)
    //     | gsum | gsumsq | (pad) | pwb.
    char* ws = (char*)d_ws;
    uint4* toep        = (uint4*)ws;
    __hip_bfloat16* rt = (__hip_bfloat16*)ws;
    float* gsum   = (float*)(ws + (size_t)33554432);
    float* gsumsq = gsum + 256;
    __hip_bfloat16* pwb = (__hip_bfloat16*)(ws + (size_t)33554432 + 4096);

    // y16 (f16, 32MiB) lives in the first half of d_out; gemm overwrites all.
    _Float16* y16 = (_Float16*)d_out;

    hipMemsetAsync(gsum, 0, 2048, stream);

    prep_kernel<<<dim3(8000), 256, 0, stream>>>(pw, pwb, dw, toep);
    dwconv_kernel<<<dim3(2048), 256, 0, stream>>>(x, toep, y16, gsum, gsumsq);
    normtrans_kernel<<<dim3(64, 8, NB), 256, 0, stream>>>(y16, gsum, gsumsq,
                                                          gamma, beta, rt);
    gemm_kernel<<<dim3(32, 2, NB), 256, 0, stream>>>(pwb, rt, out);
}

// Round 7
// 205.330 us; speedup vs baseline: 2.7669x; 1.0703x over previous
//
#include <hip/hip_runtime.h>
#include <hip/hip_bf16.h>

namespace {
constexpr int CB   = 256;   // channels
constexpr int HWp  = 4096;  // 64*64 pixels per plane
constexpr int NB   = 16;    // batch

typedef __bf16    bf16x8 __attribute__((ext_vector_type(8)));
typedef float     f32x4  __attribute__((ext_vector_type(4)));
typedef float     f32x16 __attribute__((ext_vector_type(16)));
typedef _Float16  f16x2  __attribute__((ext_vector_type(2)));
typedef _Float16  f16x8  __attribute__((ext_vector_type(8)));

typedef __attribute__((address_space(1))) void gvoid;  // global
typedef __attribute__((address_space(3))) void svoid;  // LDS

__device__ __forceinline__ unsigned int pack2(float lo, float hi) {
#if __has_builtin(__builtin_amdgcn_cvt_pkrtz)
    return __builtin_bit_cast(unsigned int, __builtin_amdgcn_cvt_pkrtz(lo, hi));
#else
    f16x2 v; v[0] = (_Float16)lo; v[1] = (_Float16)hi;
    return __builtin_bit_cast(unsigned int, v);
#endif
}

// Toeplitz table: entry = one A-fragment lane (8 f16 = 16B).
// index = ((c*31 + r)*4 + kq)*64 + lane
constexpr int TOEP_PER_C = 31 * 4 * 64;
constexpr int HALO_U32   = 94 * 64;      // per-image halo, stride 64 u32, swizzled
}

// ---------------------------------------------------------------------------
// Kernel 0: prep = BN-accumulator zeroing (bid 0) + pw fp32->bf16 (bid 0..63)
// + Toeplitz A-frag build (bid 64..7999).  A[i,k]=w[r][k-i-1], banded.
// ---------------------------------------------------------------------------
__global__ __launch_bounds__(256) void prep_kernel(
    const float* __restrict__ pw, __hip_bfloat16* __restrict__ pwb,
    const float* __restrict__ dw, uint4* __restrict__ toep,
    float* __restrict__ gsum)
{
    const int bid = blockIdx.x;
    const int tid = threadIdx.x;
    if (bid < 64) {
        if (bid == 0) { gsum[tid] = 0.f; gsum[256 + tid] = 0.f; }
        const int idx = bid * 256 + tid;
        const float4 v = reinterpret_cast<const float4*>(pw)[idx];
        union { __hip_bfloat16 h[4]; uint2 u; } pk;
        pk.h[0] = __float2bfloat16(v.x); pk.h[1] = __float2bfloat16(v.y);
        pk.h[2] = __float2bfloat16(v.z); pk.h[3] = __float2bfloat16(v.w);
        reinterpret_cast<uint2*>(pwb)[idx] = pk.u;
        return;
    }
    const int flat = (bid - 64) * 256 + tid;              // < 256*31*4*64
    const int lane = flat & 63;
    const int kq   = (flat >> 6) & 3;
    const int rc   = flat >> 8;                           // c*31 + r
    const int r    = rc % 31;
    const int c    = rc / 31;
    const int i    = lane & 31;
    const int kbase = kq * 16 + (lane >> 5) * 8;

    const float* __restrict__ wr = dw + (size_t)c * 961 + r * 31;
    union { _Float16 h[8]; uint4 u; } out;
#pragma unroll
    for (int e = 0; e < 8; ++e) {
        const int t = kbase + e - i - 1;
        out.h[e] = (t >= 0 && t <= 30) ? (_Float16)wr[t] : (_Float16)0.f;
    }
    toep[flat] = out.u;
}

// ---------------------------------------------------------------------------
// Kernel 1: depthwise 31x31 conv via MFMA, two images per block (same c).
// Halo per image: 94 x 64 u32 f16-pairs, XOR-swizzled (col ^= (row&7)<<2).
// y written as f16 into workspace.
// ---------------------------------------------------------------------------
__global__ __launch_bounds__(256, 3) void dwconv_kernel(
    const float* __restrict__ x, const uint4* __restrict__ toep,
    _Float16* __restrict__ y16, float* __restrict__ gsum, float* __restrict__ gsumsq)
{
    __shared__ unsigned int xs[2 * HALO_U32];   // 48128 B

    const int bid = blockIdx.x;           // bp*256 + c  (c low bits -> XCD = c%8)
    const int c   = bid & 255;
    const int bp  = bid >> 8;
    const int tid = threadIdx.x;

    for (int idx = tid; idx < 2 * HALO_U32 / 4; idx += 256)
        reinterpret_cast<uint4*>(xs)[idx] = uint4{0, 0, 0, 0};
    __syncthreads();

    {
        const int row = tid >> 2;
        const int q   = tid & 3;
        const int hr  = row + 15;
        const int swz = (hr & 7) << 2;
        const int p0  = (8  + q * 8) ^ swz;
        const int p1  = (12 + q * 8) ^ swz;
#pragma unroll
        for (int img = 0; img < 2; ++img) {
            const float4* src = reinterpret_cast<const float4*>(
                x + ((size_t)((bp * 2 + img) * CB + c)) * HWp + row * 64 + q * 16);
            float4 v0 = src[0], v1 = src[1], v2 = src[2], v3 = src[3];
            uint4 a, b;
            a.x = pack2(v0.x, v0.y); a.y = pack2(v0.z, v0.w);
            a.z = pack2(v1.x, v1.y); a.w = pack2(v1.z, v1.w);
            b.x = pack2(v2.x, v2.y); b.y = pack2(v2.z, v2.w);
            b.z = pack2(v3.x, v3.y); b.w = pack2(v3.z, v3.w);
            unsigned int* base = xs + img * HALO_U32 + hr * 64;
            *reinterpret_cast<uint4*>(base + p0) = a;
            *reinterpret_cast<uint4*>(base + p1) = b;
        }
    }
    __syncthreads();

    const int lane = tid & 63;
    const int wid  = tid >> 6;
    const int j    = lane & 31;
    const int half = lane >> 5;
    const int rowb = wid * 16 + (j >> 1);
    const int colb = (j & 1) * 16 + half * 4;
    const uint4* __restrict__ tp = toep + (size_t)c * TOEP_PER_C + lane;

    f32x16 acc0 = {}, acc1 = {};
    uint4 afA[4];
#pragma unroll
    for (int kq = 0; kq < 4; ++kq) afA[kq] = tp[kq * 64];

#pragma unroll 1
    for (int r = 0; r < 31; ++r) {
        uint4 afB[4];
        if (r < 30) {
#pragma unroll
            for (int kq = 0; kq < 4; ++kq) afB[kq] = tp[((r + 1) * 4 + kq) * 64];
        }
        const int row = rowb + r;
        const int swz = (row & 7) << 2;
        const unsigned int* __restrict__ xr = xs + row * 64;
        f16x8 b0[4], b1[4];
#pragma unroll
        for (int kq = 0; kq < 4; ++kq) {
            const int p = (colb + kq * 8) ^ swz;
            b0[kq] = *reinterpret_cast<const f16x8*>(xr + p);
            b1[kq] = *reinterpret_cast<const f16x8*>(xr + HALO_U32 + p);
        }
#pragma unroll
        for (int kq = 0; kq < 4; ++kq)
            acc0 = __builtin_amdgcn_mfma_f32_32x32x16_f16(
                __builtin_bit_cast(f16x8, afA[kq]), b0[kq], acc0, 0, 0, 0);
#pragma unroll
        for (int kq = 0; kq < 4; ++kq)
            acc1 = __builtin_amdgcn_mfma_f32_32x32x16_f16(
                __builtin_bit_cast(f16x8, afA[kq]), b1[kq], acc1, 0, 0, 0);
        if (r < 30) {
#pragma unroll
            for (int kq = 0; kq < 4; ++kq) afA[kq] = afB[kq];
        }
    }

    const size_t pl0 = ((size_t)(bp * 2 * CB + c)) * HWp + rowb * 64 + (j & 1) * 32 + 4 * half;
#pragma unroll
    for (int g = 0; g < 4; ++g) {
        uint2 u0, u1;
        u0.x = pack2(acc0[4 * g + 0], acc0[4 * g + 1]);
        u0.y = pack2(acc0[4 * g + 2], acc0[4 * g + 3]);
        u1.x = pack2(acc1[4 * g + 0], acc1[4 * g + 1]);
        u1.y = pack2(acc1[4 * g + 2], acc1[4 * g + 3]);
        *reinterpret_cast<uint2*>(y16 + pl0 + 8 * g)            = u0;
        *reinterpret_cast<uint2*>(y16 + pl0 + CB * HWp + 8 * g) = u1;
    }

    float s = 0.f, s2 = 0.f;
#pragma unroll
    for (int t = 0; t < 16; ++t) {
        s += acc0[t] + acc1[t];
        s2 = fmaf(acc0[t], acc0[t], s2);
        s2 = fmaf(acc1[t], acc1[t], s2);
    }
#pragma unroll
    for (int off = 32; off > 0; off >>= 1) {
        s  += __shfl_down(s,  off, 64);
        s2 += __shfl_down(s2, off, 64);
    }
    if (lane == 0) {
        atomicAdd(&gsum[c],   s);
        atomicAdd(&gsumsq[c], s2);
    }
}

// ---------------------------------------------------------------------------
// Kernel 2: fused stats-finalize + BN + ReLU + bf16 + pointwise GEMM.
// out[b][o][p] = sum_c pw[o][c] * relu(bn(y[b][c][p])).
// B-operand reg-staged from y16 with BN applied, ds_write-transposed into
// ldsB[p][c].  Double-buffered ldsA/ldsB, ONE barrier per ks.
// ---------------------------------------------------------------------------
__global__ __launch_bounds__(256, 4) void gemm_kernel(
    const __hip_bfloat16* __restrict__ pwb, const _Float16* __restrict__ y16,
    const float* __restrict__ gsum, const float* __restrict__ gsumsq,
    const float* __restrict__ gamma, const float* __restrict__ beta,
    float* __restrict__ out)
{
    __shared__ __hip_bfloat16 ldsA[2][128 * 32];   // [o-row][c], 8KB each
    __shared__ unsigned short  ldsB[2][128 * 32];  // [p-row][c] bf16 bits
    __shared__ float scsh[512];                    // sc[256] | sh[256]

    const int tid  = threadIdx.x;
    const int lane = tid & 63;
    const int wid  = tid >> 6;
    const int b    = blockIdx.z;
    const int m0   = blockIdx.y * 128;
    const int p0   = blockIdx.x * 128;
    const int wm   = wid >> 1, wn = wid & 1;

    // Stats finalize, channel tid (redundant per block; trivial VALU).
    {
        const float inv = 1.f / 65536.f;
        const float mean = gsum[tid] * inv;
        const float var  = gsumsq[tid] * inv - mean * mean;
        const float sc   = gamma[tid] * rsqrtf(var + 1e-5f);
        scsh[tid]       = sc;
        scsh[256 + tid] = beta[tid] - mean * sc;
    }

    f32x4 acc[4][4];
#pragma unroll
    for (int mi = 0; mi < 4; ++mi)
#pragma unroll
        for (int ni = 0; ni < 4; ++ni) acc[mi][ni] = {0.f, 0.f, 0.f, 0.f};

    const int srow = lane >> 2;          // A staging
    const int scol = (lane & 3) * 8;
    const int fr   = lane & 15;          // fragment reads
    const int fk   = (lane >> 4) * 8;
    const int cb   = tid & 31;           // B staging: channel-within-ks
    const int pg   = tid >> 5;           // 8 groups x 16 p rows

    const _Float16* __restrict__ yb =
        y16 + ((size_t)b * CB + cb) * HWp + p0 + pg * 16;

    // Prologue: y for ks=0 into regs, A for ks=0 into ldsA[0].
    uint4 ya0 = *reinterpret_cast<const uint4*>(yb);
    uint4 ya1 = *reinterpret_cast<const uint4*>(yb + 8);
#pragma unroll
    for (int q = 0; q < 2; ++q) {
        const int issue = wid * 2 + q;
        const int row   = issue * 16 + srow;
        __builtin_amdgcn_global_load_lds(
            (gvoid*)(pwb + (size_t)(m0 + row) * CB + scol),
            (svoid*)(&ldsA[0][issue * 512]), 16, 0, 0);
    }
    __syncthreads();   // scsh + A0 + ya ready

    for (int ks = 0; ks < 8; ++ks) {
        const int cur = ks & 1;
        // BN + ReLU + bf16 on current y regs.
        const float scv = scsh[ks * 32 + cb];
        const float shv = scsh[256 + ks * 32 + cb];
        const f16x8 h0 = __builtin_bit_cast(f16x8, ya0);
        const f16x8 h1 = __builtin_bit_cast(f16x8, ya1);
        unsigned short rb[16];
#pragma unroll
        for (int e = 0; e < 8; ++e) {
            const __hip_bfloat16 v0 = __float2bfloat16(fmaxf(fmaf((float)h0[e], scv, shv), 0.f));
            const __hip_bfloat16 v1 = __float2bfloat16(fmaxf(fmaf((float)h1[e], scv, shv), 0.f));
            rb[e]     = __builtin_bit_cast(unsigned short, v0);
            rb[8 + e] = __builtin_bit_cast(unsigned short, v1);
        }
        // Transposed LDS write: ldsB[p][c], 16 x b16 (stride 64B).
        unsigned short* bw = &ldsB[cur][(pg * 16) * 32 + cb];
#pragma unroll
        for (int e = 0; e < 16; ++e) bw[e * 32] = rb[e];

        // Prefetch next ks before the barrier (drain doubles as wait).
        if (ks < 7) {
            const _Float16* yn = yb + (size_t)(ks + 1) * 32 * HWp;
            ya0 = *reinterpret_cast<const uint4*>(yn);
            ya1 = *reinterpret_cast<const uint4*>(yn + 8);
            const int k0 = (ks + 1) * 32;
#pragma unroll
            for (int q = 0; q < 2; ++q) {
                const int issue = wid * 2 + q;
                const int row   = issue * 16 + srow;
                __builtin_amdgcn_global_load_lds(
                    (gvoid*)(pwb + (size_t)(m0 + row) * CB + k0 + scol),
                    (svoid*)(&ldsA[cur ^ 1][issue * 512]), 16, 0, 0);
            }
        }
        __syncthreads();

        bf16x8 af[4], bfv[4];
#pragma unroll
        for (int mi = 0; mi < 4; ++mi)
            af[mi] = *reinterpret_cast<const bf16x8*>(
                &ldsA[cur][(wm * 64 + mi * 16 + fr) * 32 + fk]);
#pragma unroll
        for (int ni = 0; ni < 4; ++ni)
            bfv[ni] = *reinterpret_cast<const bf16x8*>(
                &ldsB[cur][(wn * 64 + ni * 16 + fr) * 32 + fk]);

#pragma unroll
        for (int mi = 0; mi < 4; ++mi)
#pragma unroll
            for (int ni = 0; ni < 4; ++ni)
                acc[mi][ni] = __builtin_amdgcn_mfma_f32_16x16x32_bf16(
                    af[mi], bfv[ni], acc[mi][ni], 0, 0, 0);
        // no second barrier: double-buffered, next writes go to cur^1
    }

    const int frow = (lane >> 4) * 4;
#pragma unroll
    for (int mi = 0; mi < 4; ++mi)
#pragma unroll
        for (int ni = 0; ni < 4; ++ni)
#pragma unroll
            for (int v = 0; v < 4; ++v) {
                const int o = m0 + wm * 64 + mi * 16 + frow + v;
                const int p = p0 + wn * 64 + ni * 16 + fr;
                out[((size_t)(b * CB + o)) * HWp + p] = acc[mi][ni][v];
            }
}

// ---------------------------------------------------------------------------
extern "C" void kernel_launch(void* const* d_in, const int* in_sizes, int n_in,
                              void* d_out, int out_size, void* d_ws, size_t ws_size,
                              hipStream_t stream) {
    (void)in_sizes; (void)n_in; (void)out_size; (void)ws_size;
    const float* x     = (const float*)d_in[0];
    const float* dw    = (const float*)d_in[1];
    const float* gamma = (const float*)d_in[2];
    const float* beta  = (const float*)d_in[3];
    const float* pw    = (const float*)d_in[4];
    float* out = (float*)d_out;

    // toep (32.5MB) lives in d_out and dies before gemm's stores.
    // ws: y16 (32MB) | gsum(256) gsumsq(256) | pad | pwb (128KB).
    char* ws = (char*)d_ws;
    uint4* toep   = (uint4*)d_out;
    _Float16* y16 = (_Float16*)ws;
    float* gsum   = (float*)(ws + (size_t)33554432);
    float* gsumsq = gsum + 256;
    __hip_bfloat16* pwb = (__hip_bfloat16*)(ws + (size_t)33554432 + 4096);

    prep_kernel<<<dim3(8000), 256, 0, stream>>>(pw, pwb, dw, toep, gsum);
    dwconv_kernel<<<dim3(2048), 256, 0, stream>>>(x, toep, y16, gsum, gsumsq);
    gemm_kernel<<<dim3(32, 2, NB), 256, 0, stream>>>(pwb, y16, gsum, gsumsq,
                                                     gamma, beta, out);
}